// Round 1
// baseline (16876.305 us; speedup 1.0000x reference)
//
#include <hip/hip_runtime.h>
#include <math.h>

#define EF 128
#define NPTS 32768
#define KNN 8
#define MVOX 8192
#define GDIM 32
#define NVOXG (GDIM*GDIM*GDIM)   // 32768

__device__ __forceinline__ float lrelu(float x) { return x > 0.f ? x : 0.01f * x; }

// ---------- pc_conv_first: xyz[N*K,3] -> MLP(3->128 lrelu ->128) -> max over K -> lrelu ----------
__global__ void k_pc_first(const float* __restrict__ xyz,
                           const float* __restrict__ W1, const float* __restrict__ b1,
                           const float* __restrict__ W2, const float* __restrict__ b2,
                           float* __restrict__ out) {
    __shared__ float t[EF];
    int n = blockIdx.x, j = threadIdx.x;
    float m = -INFINITY;
    float b1j = b1[j], b2j = b2[j];
    float w0 = W1[j], w1 = W1[EF + j], w2 = W1[2*EF + j];
    for (int k = 0; k < KNN; ++k) {
        const float* p = xyz + (size_t)(n*KNN + k)*3;
        float s = b1j + p[0]*w0 + p[1]*w1 + p[2]*w2;
        __syncthreads();               // previous t readers done
        t[j] = lrelu(s);
        __syncthreads();
        float h = b2j;
        #pragma unroll 4
        for (int c = 0; c < EF; ++c) h += t[c] * W2[c*EF + j];
        m = fmaxf(m, h);
    }
    out[(size_t)n*EF + j] = lrelu(m);
}

// ---------- pc_res: x -> lrelu(lrelu(x@W1+b1)@W2+b2 + x), in-place ----------
__global__ void k_pc_res(float* __restrict__ feat,
                         const float* __restrict__ W1, const float* __restrict__ b1,
                         const float* __restrict__ W2, const float* __restrict__ b2) {
    __shared__ float xs[EF], t[EF];
    int r = blockIdx.x, j = threadIdx.x;
    float x = feat[(size_t)r*EF + j];
    xs[j] = x;
    __syncthreads();
    float s = b1[j];
    #pragma unroll 4
    for (int c = 0; c < EF; ++c) s += xs[c] * W1[c*EF + j];
    t[j] = lrelu(s);
    __syncthreads();
    float h = b2[j];
    #pragma unroll 4
    for (int c = 0; c < EF; ++c) h += t[c] * W2[c*EF + j];
    feat[(size_t)r*EF + j] = lrelu(h + x);
}

// ---------- pc_conv: gather neighbors, concat xyz, MLP(131->128 lrelu ->128), max over K, lrelu ----------
__global__ void k_pc_conv(const float* __restrict__ fin, const int* __restrict__ idx,
                          const float* __restrict__ xyz,
                          const float* __restrict__ W1, const float* __restrict__ b1,
                          const float* __restrict__ W2, const float* __restrict__ b2,
                          float* __restrict__ fout) {
    __shared__ float g[EF + 4], t[EF];
    int r = blockIdx.x, j = threadIdx.x;
    float m = -INFINITY;
    float b1j = b1[j], b2j = b2[j];
    for (int k = 0; k < KNN; ++k) {
        int nb = idx[r*KNN + k];
        __syncthreads();               // prev g/t readers done
        g[j] = fin[(size_t)nb*EF + j];
        if (j < 3) g[EF + j] = xyz[(size_t)(r*KNN + k)*3 + j];
        __syncthreads();
        float s = b1j;
        #pragma unroll 4
        for (int c = 0; c < EF + 3; ++c) s += g[c] * W1[c*EF + j];
        t[j] = lrelu(s);
        __syncthreads();
        float h = b2j;
        #pragma unroll 4
        for (int c = 0; c < EF; ++c) h += t[c] * W2[c*EF + j];
        m = fmaxf(m, h);
    }
    fout[(size_t)r*EF + j] = lrelu(m);
}

// ---------- min over voxel coords ----------
__global__ void k_vmin(const int* __restrict__ vx, int M, int* __restrict__ vmin) {
    __shared__ int sm[3*256];
    int t = threadIdx.x;
    int m0 = 0x7fffffff, m1 = 0x7fffffff, m2 = 0x7fffffff;
    for (int i = t; i < M; i += 256) {
        m0 = min(m0, vx[i*3+0]); m1 = min(m1, vx[i*3+1]); m2 = min(m2, vx[i*3+2]);
    }
    sm[t] = m0; sm[256+t] = m1; sm[512+t] = m2;
    __syncthreads();
    for (int s = 128; s > 0; s >>= 1) {
        if (t < s) {
            sm[t]     = min(sm[t],     sm[t+s]);
            sm[256+t] = min(sm[256+t], sm[256+t+s]);
            sm[512+t] = min(sm[512+t], sm[512+t+s]);
        }
        __syncthreads();
    }
    if (t == 0) { vmin[0] = sm[0]; vmin[1] = sm[256]; vmin[2] = sm[512]; }
}

// ---------- scatter voxel feats into dense grid [32][32][32][128] ----------
__global__ void k_scatter(const float* __restrict__ vf, const int* __restrict__ vx,
                          const int* __restrict__ vmin, float* __restrict__ grid) {
    int m = blockIdx.x, j = threadIdx.x;
    int v0 = vx[m*3+0] - vmin[0];
    int v1 = vx[m*3+1] - vmin[1];
    int v2 = vx[m*3+2] - vmin[2];
    grid[(size_t)(((v0*GDIM) + v1)*GDIM + v2)*EF + j] = vf[(size_t)m*EF + j];
}

// ---------- transpose conv weights [O][I][27] -> [27][I][O] ----------
__global__ void k_tr_w3(const float* __restrict__ W, float* __restrict__ wtr) {
    int t = blockIdx.x*256 + threadIdx.x;
    if (t >= 27*EF*EF) return;
    int o = t & 127, i = (t >> 7) & 127, k = t >> 14;
    wtr[t] = W[(size_t)(o*EF + i)*27 + k];
}
// ---------- transpose [O][I] -> [I][O] ----------
__global__ void k_tr_w1(const float* __restrict__ W, float* __restrict__ wtr) {
    int t = blockIdx.x*256 + threadIdx.x;
    int o = t & 127, i = t >> 7;
    wtr[t] = W[o*EF + i];
}

// ---------- conv3d 3x3x3 SAME + bias + lrelu; 8 voxels along x per block ----------
__global__ void k_conv3(const float* __restrict__ gin, const float* __restrict__ wtr,
                        const float* __restrict__ bias, float* __restrict__ gout) {
    int b = blockIdx.x;
    int x0 = (b & 3) * 8;
    int y  = (b >> 2) & 31;
    int z  = b >> 7;
    int co = threadIdx.x;
    float acc[8];
    float bb = bias[co];
    #pragma unroll
    for (int i = 0; i < 8; ++i) acc[i] = bb;
    for (int dz = -1; dz <= 1; ++dz) {
        int zz = z + dz; if ((unsigned)zz >= (unsigned)GDIM) continue;
        for (int dy = -1; dy <= 1; ++dy) {
            int yy = y + dy; if ((unsigned)yy >= (unsigned)GDIM) continue;
            const float* base  = gin + (size_t)((zz*GDIM + yy)*GDIM)*EF;
            const float* wbase = wtr + (size_t)((dz+1)*9 + (dy+1)*3)*EF*EF;
            for (int ci = 0; ci < EF; ++ci) {
                float xv[10];
                #pragma unroll
                for (int u = 0; u < 10; ++u) {
                    int xx = x0 - 1 + u;
                    float v = 0.f;
                    if ((unsigned)xx < (unsigned)GDIM) v = base[(size_t)xx*EF + ci];
                    xv[u] = v;
                }
                #pragma unroll
                for (int dx = 0; dx < 3; ++dx) {
                    float w = wbase[(size_t)dx*EF*EF + ci*EF + co];
                    #pragma unroll
                    for (int i = 0; i < 8; ++i) acc[i] += xv[i + dx] * w;
                }
            }
        }
    }
    float* outp = gout + (size_t)((z*GDIM + y)*GDIM + x0)*EF + co;
    #pragma unroll
    for (int i = 0; i < 8; ++i) outp[(size_t)i*EF] = lrelu(acc[i]);
}

// ---------- 1x1x1 conv + bias + residual + lrelu (in-place on x) ----------
__global__ void k_conv1res(const float* __restrict__ yin, const float* __restrict__ wtr2,
                           const float* __restrict__ bias, float* __restrict__ xio) {
    __shared__ float t[EF];
    int v = blockIdx.x, co = threadIdx.x;
    t[co] = yin[(size_t)v*EF + co];
    __syncthreads();
    float h = bias[co];
    #pragma unroll 4
    for (int ci = 0; ci < EF; ++ci) h += t[ci] * wtr2[ci*EF + co];
    float x = xio[(size_t)v*EF + co];
    xio[(size_t)v*EF + co] = lrelu(h + x);
}

// ---------- gather + lin1 + lin2 + linb + sigmoid ----------
__global__ void k_final(const float* __restrict__ grid, const int* __restrict__ vx,
                        const int* __restrict__ vmin,
                        const float* __restrict__ W1, const float* __restrict__ b1,
                        const float* __restrict__ W2, const float* __restrict__ b2,
                        const float* __restrict__ W3, const float* __restrict__ b3,
                        float* __restrict__ out) {
    __shared__ float xs[EF], t[EF];
    int m = blockIdx.x, j = threadIdx.x;
    int v0 = vx[m*3+0] - vmin[0];
    int v1 = vx[m*3+1] - vmin[1];
    int v2 = vx[m*3+2] - vmin[2];
    xs[j] = grid[(size_t)(((v0*GDIM) + v1)*GDIM + v2)*EF + j];
    __syncthreads();
    float s = b1[j];
    #pragma unroll 4
    for (int c = 0; c < EF; ++c) s += xs[c] * W1[c*EF + j];
    t[j] = lrelu(s);
    __syncthreads();
    float s2 = b2[j];
    #pragma unroll 4
    for (int c = 0; c < EF; ++c) s2 += t[c] * W2[c*EF + j];
    __syncthreads();
    xs[j] = lrelu(s2);
    __syncthreads();
    if (j < 3) {
        float o = b3[j];
        #pragma unroll 4
        for (int c = 0; c < EF; ++c) o += xs[c] * W3[c*3 + j];
        out[(size_t)m*3 + j] = 1.f / (1.f + expf(-o));
    }
}

extern "C" void kernel_launch(void* const* d_in, const int* in_sizes, int n_in,
                              void* d_out, int out_size, void* d_ws, size_t ws_size,
                              hipStream_t stream) {
    const int*   pc_idx  = (const int*)  d_in[0];
    const float* pc_xyz  = (const float*)d_in[1];
    const int*   vox_int = (const int*)  d_in[2];
    const int*   vox_idx = (const int*)  d_in[3];
    const float* vox_xyz = (const float*)d_in[4];
    const float* pcf_W1  = (const float*)d_in[5];
    const float* pcf_b1  = (const float*)d_in[6];
    const float* pcf_W2  = (const float*)d_in[7];
    const float* pcf_b2  = (const float*)d_in[8];
    const float* pcres_W1 = (const float*)d_in[9];
    const float* pcres_b1 = (const float*)d_in[10];
    const float* pcres_W2 = (const float*)d_in[11];
    const float* pcres_b2 = (const float*)d_in[12];
    const float* pcc_W1  = (const float*)d_in[13];
    const float* pcc_b1  = (const float*)d_in[14];
    const float* pcc_W2  = (const float*)d_in[15];
    const float* pcc_b2  = (const float*)d_in[16];
    const float* r3_Wc1  = (const float*)d_in[17];
    const float* r3_bc1  = (const float*)d_in[18];
    const float* r3_Wc2  = (const float*)d_in[19];
    const float* r3_bc2  = (const float*)d_in[20];
    const float* lin1_W  = (const float*)d_in[21];
    const float* lin1_b  = (const float*)d_in[22];
    const float* lin2_W  = (const float*)d_in[23];
    const float* lin2_b  = (const float*)d_in[24];
    const float* linb_W  = (const float*)d_in[25];
    const float* linb_b  = (const float*)d_in[26];

    float* w = (float*)d_ws;
    float* featA = w;                                   // 32768*128
    float* featB = featA + (size_t)NPTS*EF;             // 32768*128
    float* gridA = featB + (size_t)NPTS*EF;             // 32768*128
    float* gridB = gridA + (size_t)NVOXG*EF;            // 32768*128
    float* wtr   = gridB + (size_t)NVOXG*EF;            // 27*128*128
    float* wtr2  = wtr + 27*EF*EF;                      // 128*128
    int*   vmin  = (int*)(wtr2 + EF*EF);                // 3 ints

    // ---- point-cloud stack ----
    k_pc_first<<<NPTS, 128, 0, stream>>>(pc_xyz, pcf_W1, pcf_b1, pcf_W2, pcf_b2, featA);
    k_pc_res<<<NPTS, 128, 0, stream>>>(featA, pcres_W1, pcres_b1, pcres_W2, pcres_b2);
    float* cur = featA; float* nxt = featB;
    for (int i = 0; i < 5; ++i) {
        k_pc_conv<<<NPTS, 128, 0, stream>>>(cur, pc_idx, pc_xyz,
                                            pcc_W1 + (size_t)i*(EF+3)*EF, pcc_b1 + i*EF,
                                            pcc_W2 + (size_t)i*EF*EF,    pcc_b2 + i*EF, nxt);
        k_pc_res<<<NPTS, 128, 0, stream>>>(nxt,
                                           pcres_W1 + (size_t)(i+1)*EF*EF, pcres_b1 + (i+1)*EF,
                                           pcres_W2 + (size_t)(i+1)*EF*EF, pcres_b2 + (i+1)*EF);
        float* tmp = cur; cur = nxt; nxt = tmp;
    }
    k_pc_conv<<<MVOX, 128, 0, stream>>>(cur, vox_idx, vox_xyz,
                                        pcc_W1 + (size_t)5*(EF+3)*EF, pcc_b1 + 5*EF,
                                        pcc_W2 + (size_t)5*EF*EF,    pcc_b2 + 5*EF, nxt);
    k_pc_res<<<MVOX, 128, 0, stream>>>(nxt,
                                       pcres_W1 + (size_t)6*EF*EF, pcres_b1 + 6*EF,
                                       pcres_W2 + (size_t)6*EF*EF, pcres_b2 + 6*EF);
    float* voxfeat = nxt;

    // ---- scatter to dense grid ----
    k_vmin<<<1, 256, 0, stream>>>(vox_int, MVOX, vmin);
    hipMemsetAsync(gridA, 0, (size_t)NVOXG*EF*sizeof(float), stream);
    k_scatter<<<MVOX, 128, 0, stream>>>(voxfeat, vox_int, vmin, gridA);

    // ---- 8 x resnet_block_rec3 ----
    for (int i = 0; i < 8; ++i) {
        k_tr_w3<<<(27*EF*EF + 255)/256, 256, 0, stream>>>(r3_Wc1 + (size_t)i*27*EF*EF, wtr);
        k_conv3<<<NVOXG/8, 128, 0, stream>>>(gridA, wtr, r3_bc1 + i*EF, gridB);
        k_tr_w1<<<(EF*EF + 255)/256, 256, 0, stream>>>(r3_Wc2 + (size_t)i*EF*EF, wtr2);
        k_conv1res<<<NVOXG, 128, 0, stream>>>(gridB, wtr2, r3_bc2 + i*EF, gridA);
    }

    // ---- head ----
    k_final<<<MVOX, 128, 0, stream>>>(gridA, vox_int, vmin,
                                      lin1_W, lin1_b, lin2_W, lin2_b, linb_W, linb_b,
                                      (float*)d_out);
}

// Round 2
// 1713.627 us; speedup vs baseline: 9.8483x; 9.8483x over previous
//
#include <hip/hip_runtime.h>
#include <math.h>

#define EF 128
#define NPTS 32768
#define KNN 8
#define MVOX 8192
#define GDIM 32
#define NVOXG (GDIM*GDIM*GDIM)

typedef __attribute__((ext_vector_type(8))) short bfrag;   // 8 x bf16
typedef __attribute__((ext_vector_type(4))) float f32x4;

__device__ __forceinline__ float lrelu(float x) { return x > 0.f ? x : 0.01f * x; }
__device__ __forceinline__ short f2b(float f) {            // fp32 -> bf16 (RNE)
    unsigned u = __float_as_uint(f);
    return (short)((u + 0x7fff + ((u >> 16) & 1)) >> 16);
}
#define MFMA(a,b,c) __builtin_amdgcn_mfma_f32_16x16x32_bf16((a),(b),(c),0,0,0)

// ---------------- weight packing: W[k][col] (strided) -> [step][ct][lane][8] bf16 ----------------
__global__ void k_pack_w(const float* __restrict__ src, short* __restrict__ dst,
                         int K_real, int n_steps, int k_str, int c_str) {
    int t = blockIdx.x * 256 + threadIdx.x;
    int total = n_steps * 4096;
    if (t >= total) return;
    int r = t & 7, l = (t >> 3) & 63, ct = (t >> 9) & 7, s = t >> 12;
    int k = s * 32 + (l >> 4) * 8 + r;
    int col = ct * 16 + (l & 15);
    float v = (k < K_real) ? src[(size_t)k * k_str + (size_t)col * c_str] : 0.f;
    dst[t] = f2b(v);
}
// conv3x3x3 weights [o][ci][27] -> [tap*4+cc][ct][lane][8]
__global__ void k_pack_wc1(const float* __restrict__ src, short* __restrict__ dst) {
    int t = blockIdx.x * 256 + threadIdx.x;
    if (t >= 108 * 4096) return;
    int r = t & 7, l = (t >> 3) & 63, ct = (t >> 9) & 7, s = t >> 12;
    int tap = s >> 2;
    int ci = (s & 3) * 32 + (l >> 4) * 8 + r;
    int col = ct * 16 + (l & 15);
    dst[t] = f2b(src[((size_t)col * 128 + ci) * 27 + tap]);
}

// ---------------- pc_conv_first (3->128 VALU, 128->128 MFMA, maxpool) ----------------
__global__ __launch_bounds__(256) void k_pcfirst(
    const float* __restrict__ xyz, const float* __restrict__ W1, const float* __restrict__ b1,
    const short* __restrict__ w2p, const float* __restrict__ b2,
    float* __restrict__ out32, short* __restrict__ out16) {
    __shared__ __align__(16) char t_raw[4 * 4096];
    int wid = threadIdx.x >> 6, lane = threadIdx.x & 63, lrow = lane & 15, lq = lane >> 4;
    int rowbase = blockIdx.x * 64 + wid * 16;
    int grow = rowbase + lrow;
    float x0 = xyz[grow * 3], y0 = xyz[grow * 3 + 1], z0 = xyz[grow * 3 + 2];
    char* tb = t_raw + wid * 4096;
    #pragma unroll 8
    for (int j = 0; j < 32; ++j) {
        int col = lq * 32 + j;
        float v = lrelu(b1[col] + x0 * W1[col] + y0 * W1[128 + col] + z0 * W1[256 + col]);
        *(short*)(tb + lrow * 256 + ((col * 2) ^ ((lrow & 7) << 4))) = f2b(v);
    }
    __syncthreads();
    float bb2[8];
    #pragma unroll
    for (int ct = 0; ct < 8; ++ct) bb2[ct] = b2[ct * 16 + lrow];
    f32x4 zv = {0.f, 0.f, 0.f, 0.f};
    f32x4 acc[8];
    #pragma unroll
    for (int ct = 0; ct < 8; ++ct) acc[ct] = zv;
    const bfrag* bp2 = (const bfrag*)w2p;
    #pragma unroll
    for (int s = 0; s < 4; ++s) {
        bfrag av = *(const bfrag*)(tb + lrow * 256 + (((s * 32 + lq * 8) * 2) ^ ((lrow & 7) << 4)));
        #pragma unroll
        for (int ct = 0; ct < 8; ++ct) acc[ct] = MFMA(av, bp2[(s * 8 + ct) * 64 + lane], acc[ct]);
    }
    #pragma unroll
    for (int ct = 0; ct < 8; ++ct) {
        float m = -INFINITY;
        #pragma unroll
        for (int r = 0; r < 4; ++r) m = fmaxf(m, acc[ct][r] + bb2[ct]);
        m = fmaxf(m, __shfl_xor(m, 16, 64));
        if ((lq & 1) == 0) {
            int p = (rowbase >> 3) + (lq >> 1);
            float v = lrelu(m);
            out32[(size_t)p * 128 + ct * 16 + lrow] = v;
            out16[(size_t)p * 128 + ct * 16 + lrow] = f2b(v);
        }
    }
}

// ---------------- pc_conv (gather + 131->128 + 128->128 + maxpool) ----------------
__global__ __launch_bounds__(256) void k_pcconv(
    const short* __restrict__ fin16, const int* __restrict__ idx, const float* __restrict__ xyz,
    const short* __restrict__ w1p, const float* __restrict__ b1,
    const short* __restrict__ w2p, const float* __restrict__ b2,
    float* __restrict__ out32, short* __restrict__ out16) {
    __shared__ __align__(16) char t_raw[4 * 4096];
    int wid = threadIdx.x >> 6, lane = threadIdx.x & 63, lrow = lane & 15, lq = lane >> 4;
    int rowbase = blockIdx.x * 64 + wid * 16;
    int grow = rowbase + lrow;
    int nb = idx[grow];
    const bfrag* ap = (const bfrag*)(fin16 + (size_t)nb * 128) + lq;
    bfrag a[4];
    a[0] = ap[0]; a[1] = ap[4]; a[2] = ap[8]; a[3] = ap[12];
    bfrag a4;
    #pragma unroll
    for (int r = 0; r < 8; ++r) a4[r] = 0;
    if (lq == 0) {
        a4[0] = f2b(xyz[grow * 3]); a4[1] = f2b(xyz[grow * 3 + 1]); a4[2] = f2b(xyz[grow * 3 + 2]);
    }
    float bb1[8], bb2[8];
    #pragma unroll
    for (int ct = 0; ct < 8; ++ct) { bb1[ct] = b1[ct * 16 + lrow]; bb2[ct] = b2[ct * 16 + lrow]; }
    f32x4 zv = {0.f, 0.f, 0.f, 0.f};
    f32x4 acc[8];
    #pragma unroll
    for (int ct = 0; ct < 8; ++ct) acc[ct] = zv;
    const bfrag* bp1 = (const bfrag*)w1p;
    #pragma unroll
    for (int s = 0; s < 5; ++s) {
        bfrag av = (s < 4) ? a[s] : a4;
        #pragma unroll
        for (int ct = 0; ct < 8; ++ct) acc[ct] = MFMA(av, bp1[(s * 8 + ct) * 64 + lane], acc[ct]);
    }
    char* tb = t_raw + wid * 4096;
    #pragma unroll
    for (int ct = 0; ct < 8; ++ct)
        #pragma unroll
        for (int r = 0; r < 4; ++r) {
            int row = lq * 4 + r, col = ct * 16 + lrow;
            float v = lrelu(acc[ct][r] + bb1[ct]);
            *(short*)(tb + row * 256 + ((col * 2) ^ ((row & 7) << 4))) = f2b(v);
        }
    __syncthreads();
    f32x4 acc2[8];
    #pragma unroll
    for (int ct = 0; ct < 8; ++ct) acc2[ct] = zv;
    const bfrag* bp2 = (const bfrag*)w2p;
    #pragma unroll
    for (int s = 0; s < 4; ++s) {
        bfrag av = *(const bfrag*)(tb + lrow * 256 + (((s * 32 + lq * 8) * 2) ^ ((lrow & 7) << 4)));
        #pragma unroll
        for (int ct = 0; ct < 8; ++ct) acc2[ct] = MFMA(av, bp2[(s * 8 + ct) * 64 + lane], acc2[ct]);
    }
    #pragma unroll
    for (int ct = 0; ct < 8; ++ct) {
        float m = -INFINITY;
        #pragma unroll
        for (int r = 0; r < 4; ++r) m = fmaxf(m, acc2[ct][r] + bb2[ct]);
        m = fmaxf(m, __shfl_xor(m, 16, 64));
        if ((lq & 1) == 0) {
            int p = (rowbase >> 3) + (lq >> 1);
            float v = lrelu(m);
            out32[(size_t)p * 128 + ct * 16 + lrow] = v;
            out16[(size_t)p * 128 + ct * 16 + lrow] = f2b(v);
        }
    }
}

// ---------------- pc_res (x -> lrelu(lrelu(xW1+b1)W2+b2 + x)) ----------------
__global__ __launch_bounds__(256) void k_pcres(
    const float* __restrict__ fin32, const short* __restrict__ fin16,
    const short* __restrict__ w1p, const float* __restrict__ b1,
    const short* __restrict__ w2p, const float* __restrict__ b2,
    float* __restrict__ out32, short* __restrict__ out16) {
    __shared__ __align__(16) char t_raw[4 * 4096];
    int wid = threadIdx.x >> 6, lane = threadIdx.x & 63, lrow = lane & 15, lq = lane >> 4;
    int rowbase = blockIdx.x * 64 + wid * 16;
    const bfrag* ap = (const bfrag*)(fin16 + (size_t)(rowbase + lrow) * 128) + lq;
    bfrag a[4];
    a[0] = ap[0]; a[1] = ap[4]; a[2] = ap[8]; a[3] = ap[12];
    float bb1[8], bb2[8];
    #pragma unroll
    for (int ct = 0; ct < 8; ++ct) { bb1[ct] = b1[ct * 16 + lrow]; bb2[ct] = b2[ct * 16 + lrow]; }
    f32x4 zv = {0.f, 0.f, 0.f, 0.f};
    f32x4 acc[8];
    #pragma unroll
    for (int ct = 0; ct < 8; ++ct) acc[ct] = zv;
    const bfrag* bp1 = (const bfrag*)w1p;
    #pragma unroll
    for (int s = 0; s < 4; ++s)
        #pragma unroll
        for (int ct = 0; ct < 8; ++ct) acc[ct] = MFMA(a[s], bp1[(s * 8 + ct) * 64 + lane], acc[ct]);
    char* tb = t_raw + wid * 4096;
    #pragma unroll
    for (int ct = 0; ct < 8; ++ct)
        #pragma unroll
        for (int r = 0; r < 4; ++r) {
            int row = lq * 4 + r, col = ct * 16 + lrow;
            float v = lrelu(acc[ct][r] + bb1[ct]);
            *(short*)(tb + row * 256 + ((col * 2) ^ ((row & 7) << 4))) = f2b(v);
        }
    __syncthreads();
    f32x4 acc2[8];
    #pragma unroll
    for (int ct = 0; ct < 8; ++ct) acc2[ct] = zv;
    const bfrag* bp2 = (const bfrag*)w2p;
    #pragma unroll
    for (int s = 0; s < 4; ++s) {
        bfrag av = *(const bfrag*)(tb + lrow * 256 + (((s * 32 + lq * 8) * 2) ^ ((lrow & 7) << 4)));
        #pragma unroll
        for (int ct = 0; ct < 8; ++ct) acc2[ct] = MFMA(av, bp2[(s * 8 + ct) * 64 + lane], acc2[ct]);
    }
    #pragma unroll
    for (int ct = 0; ct < 8; ++ct)
        #pragma unroll
        for (int r = 0; r < 4; ++r) {
            int row = lq * 4 + r, col = ct * 16 + lrow;
            size_t o = (size_t)(rowbase + row) * 128 + col;
            float v = lrelu(acc2[ct][r] + bb2[ct] + fin32[o]);
            out32[o] = v; out16[o] = f2b(v);
        }
}

// ---------------- conv3d 3x3x3 implicit GEMM + bias lrelu + 1x1 conv + residual + lrelu ----------------
__global__ __launch_bounds__(256) void k_conv3(
    const float* __restrict__ gin32, const short* __restrict__ gin16,
    const short* __restrict__ w1p, const float* __restrict__ b1,
    const short* __restrict__ w2p, const float* __restrict__ b2,
    float* __restrict__ gout32, short* __restrict__ gout16) {
    __shared__ __align__(16) char t_raw[4 * 4096];
    int wid = threadIdx.x >> 6, lane = threadIdx.x & 63, lrow = lane & 15, lq = lane >> 4;
    int line = blockIdx.x * 2 + (wid >> 1);
    int va = line >> 5, vb = line & 31;
    int c0 = (wid & 1) * 16;
    int vc = c0 + lrow;
    float bb1[8], bb2[8];
    #pragma unroll
    for (int ct = 0; ct < 8; ++ct) { bb1[ct] = b1[ct * 16 + lrow]; bb2[ct] = b2[ct * 16 + lrow]; }
    f32x4 zv = {0.f, 0.f, 0.f, 0.f};
    f32x4 acc[8];
    #pragma unroll
    for (int ct = 0; ct < 8; ++ct) acc[ct] = zv;
    bfrag zf;
    #pragma unroll
    for (int r = 0; r < 8; ++r) zf[r] = 0;
    const bfrag* bp1 = (const bfrag*)w1p;
    for (int tap = 0; tap < 27; ++tap) {
        int da = tap / 9 - 1, db = (tap / 3) % 3 - 1, dc = tap % 3 - 1;
        int aa = va + da, bb = vb + db, cc = vc + dc;
        bool ok = ((unsigned)aa < 32u) && ((unsigned)bb < 32u) && ((unsigned)cc < 32u);
        size_t off = ok ? ((size_t)((aa * 32 + bb) * 32 + cc) * 128) : 0;
        const bfrag* ap = (const bfrag*)(gin16 + off) + lq;
        bfrag a4[4];
        #pragma unroll
        for (int s = 0; s < 4; ++s) { bfrag t = ap[s * 4]; a4[s] = ok ? t : zf; }
        #pragma unroll
        for (int s = 0; s < 4; ++s)
            #pragma unroll
            for (int ct = 0; ct < 8; ++ct)
                acc[ct] = MFMA(a4[s], bp1[((tap * 4 + s) * 8 + ct) * 64 + lane], acc[ct]);
    }
    char* tb = t_raw + wid * 4096;
    #pragma unroll
    for (int ct = 0; ct < 8; ++ct)
        #pragma unroll
        for (int r = 0; r < 4; ++r) {
            int row = lq * 4 + r, col = ct * 16 + lrow;
            float v = lrelu(acc[ct][r] + bb1[ct]);
            *(short*)(tb + row * 256 + ((col * 2) ^ ((row & 7) << 4))) = f2b(v);
        }
    __syncthreads();
    f32x4 acc2[8];
    #pragma unroll
    for (int ct = 0; ct < 8; ++ct) acc2[ct] = zv;
    const bfrag* bp2 = (const bfrag*)w2p;
    #pragma unroll
    for (int s = 0; s < 4; ++s) {
        bfrag av = *(const bfrag*)(tb + lrow * 256 + (((s * 32 + lq * 8) * 2) ^ ((lrow & 7) << 4)));
        #pragma unroll
        for (int ct = 0; ct < 8; ++ct) acc2[ct] = MFMA(av, bp2[(s * 8 + ct) * 64 + lane], acc2[ct]);
    }
    size_t vbase = (size_t)((va * 32 + vb) * 32) * 128;
    #pragma unroll
    for (int ct = 0; ct < 8; ++ct)
        #pragma unroll
        for (int r = 0; r < 4; ++r) {
            int row = lq * 4 + r, col = ct * 16 + lrow;
            size_t o = vbase + (size_t)(c0 + row) * 128 + col;
            float v = lrelu(acc2[ct][r] + bb2[ct] + gin32[o]);
            gout32[o] = v; gout16[o] = f2b(v);
        }
}

// ---------------- small kernels ----------------
__global__ void k_vmin(const int* __restrict__ vx, int M, int* __restrict__ vmin) {
    __shared__ int sm[3 * 256];
    int t = threadIdx.x;
    int m0 = 0x7fffffff, m1 = 0x7fffffff, m2 = 0x7fffffff;
    for (int i = t; i < M; i += 256) {
        m0 = min(m0, vx[i * 3 + 0]); m1 = min(m1, vx[i * 3 + 1]); m2 = min(m2, vx[i * 3 + 2]);
    }
    sm[t] = m0; sm[256 + t] = m1; sm[512 + t] = m2;
    __syncthreads();
    for (int s = 128; s > 0; s >>= 1) {
        if (t < s) {
            sm[t] = min(sm[t], sm[t + s]);
            sm[256 + t] = min(sm[256 + t], sm[256 + t + s]);
            sm[512 + t] = min(sm[512 + t], sm[512 + t + s]);
        }
        __syncthreads();
    }
    if (t == 0) { vmin[0] = sm[0]; vmin[1] = sm[256]; vmin[2] = sm[512]; }
}

__global__ void k_scatter(const float* __restrict__ vf, const int* __restrict__ vx,
                          const int* __restrict__ vmin, float* __restrict__ g32, short* __restrict__ g16) {
    int m = blockIdx.x, j = threadIdx.x;
    int v0 = vx[m * 3 + 0] - vmin[0];
    int v1 = vx[m * 3 + 1] - vmin[1];
    int v2 = vx[m * 3 + 2] - vmin[2];
    size_t o = (size_t)(((v0 * GDIM) + v1) * GDIM + v2) * EF + j;
    float v = vf[(size_t)m * EF + j];
    g32[o] = v; g16[o] = f2b(v);
}

__global__ void k_final(const float* __restrict__ grid, const int* __restrict__ vx,
                        const int* __restrict__ vmin,
                        const float* __restrict__ W1, const float* __restrict__ b1,
                        const float* __restrict__ W2, const float* __restrict__ b2,
                        const float* __restrict__ W3, const float* __restrict__ b3,
                        float* __restrict__ out) {
    __shared__ float xs[EF], t[EF];
    int m = blockIdx.x, j = threadIdx.x;
    int v0 = vx[m * 3 + 0] - vmin[0];
    int v1 = vx[m * 3 + 1] - vmin[1];
    int v2 = vx[m * 3 + 2] - vmin[2];
    xs[j] = grid[(size_t)(((v0 * GDIM) + v1) * GDIM + v2) * EF + j];
    __syncthreads();
    float s = b1[j];
    #pragma unroll 4
    for (int c = 0; c < EF; ++c) s += xs[c] * W1[c * EF + j];
    t[j] = lrelu(s);
    __syncthreads();
    float s2 = b2[j];
    #pragma unroll 4
    for (int c = 0; c < EF; ++c) s2 += t[c] * W2[c * EF + j];
    __syncthreads();
    xs[j] = lrelu(s2);
    __syncthreads();
    if (j < 3) {
        float o = b3[j];
        for (int c = 0; c < EF; ++c) o += xs[c] * W3[c * 3 + j];
        out[(size_t)m * 3 + j] = 1.f / (1.f + expf(-o));
    }
}

extern "C" void kernel_launch(void* const* d_in, const int* in_sizes, int n_in,
                              void* d_out, int out_size, void* d_ws, size_t ws_size,
                              hipStream_t stream) {
    const int*   pc_idx  = (const int*)  d_in[0];
    const float* pc_xyz  = (const float*)d_in[1];
    const int*   vox_int = (const int*)  d_in[2];
    const int*   vox_idx = (const int*)  d_in[3];
    const float* vox_xyz = (const float*)d_in[4];
    const float* pcf_W1  = (const float*)d_in[5];
    const float* pcf_b1  = (const float*)d_in[6];
    const float* pcf_W2  = (const float*)d_in[7];
    const float* pcf_b2  = (const float*)d_in[8];
    const float* pcres_W1 = (const float*)d_in[9];
    const float* pcres_b1 = (const float*)d_in[10];
    const float* pcres_W2 = (const float*)d_in[11];
    const float* pcres_b2 = (const float*)d_in[12];
    const float* pcc_W1  = (const float*)d_in[13];
    const float* pcc_b1  = (const float*)d_in[14];
    const float* pcc_W2  = (const float*)d_in[15];
    const float* pcc_b2  = (const float*)d_in[16];
    const float* r3_Wc1  = (const float*)d_in[17];
    const float* r3_bc1  = (const float*)d_in[18];
    const float* r3_Wc2  = (const float*)d_in[19];
    const float* r3_bc2  = (const float*)d_in[20];
    const float* lin1_W  = (const float*)d_in[21];
    const float* lin1_b  = (const float*)d_in[22];
    const float* lin2_W  = (const float*)d_in[23];
    const float* lin2_b  = (const float*)d_in[24];
    const float* linb_W  = (const float*)d_in[25];
    const float* linb_b  = (const float*)d_in[26];

    const size_t NE = (size_t)NPTS * EF;   // 4M elements
    float* A32 = (float*)d_ws;
    float* B32 = A32 + NE;
    short* A16 = (short*)(B32 + NE);
    short* B16 = A16 + NE;
    float* Y32 = (float*)(B16 + NE);
    short* Y16 = (short*)(Y32 + NE);
    short* pcf_w2p = Y16 + NE;
    short* pcc_w1p = pcf_w2p + 4 * 4096;       // 6 layers x 5 steps
    short* pcc_w2p = pcc_w1p + 6 * 5 * 4096;   // 6 x 4
    short* pcr_w1p = pcc_w2p + 6 * 4 * 4096;   // 7 x 4
    short* pcr_w2p = pcr_w1p + 7 * 4 * 4096;
    short* wc2p    = pcr_w2p + 7 * 4 * 4096;   // 8 x 4
    short* wc1p    = wc2p    + 8 * 4 * 4096;   // 108 steps (one layer at a time)
    int*   vmin    = (int*)(wc1p + 108 * 4096);

    // ---- pack weights ----
    k_pack_w<<<64, 256, 0, stream>>>(pcf_W2, pcf_w2p, 128, 4, 128, 1);
    for (int i = 0; i < 6; ++i) {
        k_pack_w<<<80, 256, 0, stream>>>(pcc_W1 + (size_t)i * 131 * 128, pcc_w1p + (size_t)i * 5 * 4096, 131, 5, 128, 1);
        k_pack_w<<<64, 256, 0, stream>>>(pcc_W2 + (size_t)i * 128 * 128, pcc_w2p + (size_t)i * 4 * 4096, 128, 4, 128, 1);
    }
    for (int i = 0; i < 7; ++i) {
        k_pack_w<<<64, 256, 0, stream>>>(pcres_W1 + (size_t)i * 128 * 128, pcr_w1p + (size_t)i * 4 * 4096, 128, 4, 128, 1);
        k_pack_w<<<64, 256, 0, stream>>>(pcres_W2 + (size_t)i * 128 * 128, pcr_w2p + (size_t)i * 4 * 4096, 128, 4, 128, 1);
    }
    for (int i = 0; i < 8; ++i)
        k_pack_w<<<64, 256, 0, stream>>>(r3_Wc2 + (size_t)i * 128 * 128, wc2p + (size_t)i * 4 * 4096, 128, 4, 1, 128);

    // ---- point-cloud stack (A/B ping-pong; fp32 master + bf16 mirror) ----
    k_pcfirst<<<NPTS * KNN / 64, 256, 0, stream>>>(pc_xyz, pcf_W1, pcf_b1, pcf_w2p, pcf_b2, A32, A16);
    k_pcres<<<NPTS / 64, 256, 0, stream>>>(A32, A16, pcr_w1p, pcres_b1, pcr_w2p, pcres_b2, B32, B16);
    for (int i = 0; i < 5; ++i) {
        k_pcconv<<<NPTS * KNN / 64, 256, 0, stream>>>(B16, pc_idx, pc_xyz,
            pcc_w1p + (size_t)i * 5 * 4096, pcc_b1 + i * EF,
            pcc_w2p + (size_t)i * 4 * 4096, pcc_b2 + i * EF, A32, A16);
        k_pcres<<<NPTS / 64, 256, 0, stream>>>(A32, A16,
            pcr_w1p + (size_t)(i + 1) * 4 * 4096, pcres_b1 + (i + 1) * EF,
            pcr_w2p + (size_t)(i + 1) * 4 * 4096, pcres_b2 + (i + 1) * EF, B32, B16);
    }
    k_pcconv<<<MVOX * KNN / 64, 256, 0, stream>>>(B16, vox_idx, vox_xyz,
        pcc_w1p + (size_t)5 * 5 * 4096, pcc_b1 + 5 * EF,
        pcc_w2p + (size_t)5 * 4 * 4096, pcc_b2 + 5 * EF, A32, A16);
    k_pcres<<<MVOX / 64, 256, 0, stream>>>(A32, A16,
        pcr_w1p + (size_t)6 * 4 * 4096, pcres_b1 + 6 * EF,
        pcr_w2p + (size_t)6 * 4 * 4096, pcres_b2 + 6 * EF, B32, B16);
    // voxfeat now in B32 (rows 0..MVOX-1); A buffers are dead -> reuse as grid X

    k_vmin<<<1, 256, 0, stream>>>(vox_int, MVOX, vmin);
    hipMemsetAsync(A32, 0, NE * sizeof(float), stream);
    hipMemsetAsync(A16, 0, NE * sizeof(short), stream);
    k_scatter<<<MVOX, 128, 0, stream>>>(B32, vox_int, vmin, A32, A16);

    // ---- 8 x resnet_block_rec3 (X = A, Y = Y; ping-pong) ----
    float* cur32 = A32; short* cur16 = A16;
    float* nxt32 = Y32; short* nxt16 = Y16;
    for (int i = 0; i < 8; ++i) {
        k_pack_wc1<<<1728, 256, 0, stream>>>(r3_Wc1 + (size_t)i * 128 * 128 * 27, wc1p);
        k_conv3<<<1024 / 2, 256, 0, stream>>>(cur32, cur16, wc1p, r3_bc1 + i * EF,
                                              wc2p + (size_t)i * 4 * 4096, r3_bc2 + i * EF,
                                              nxt32, nxt16);
        float* t32 = cur32; cur32 = nxt32; nxt32 = t32;
        short* t16 = cur16; cur16 = nxt16; nxt16 = t16;
    }

    // ---- head ----
    k_final<<<MVOX, 128, 0, stream>>>(cur32, vox_int, vmin,
                                      lin1_W, lin1_b, lin2_W, lin2_b, linb_W, linb_b,
                                      (float*)d_out);
}